// Round 1
// baseline (280.404 us; speedup 1.0000x reference)
//
#include <hip/hip_runtime.h>
#include <math.h>

#define EPSf 1e-10f
#define IMG_N 64
#define IMG_H 512
#define IMG_W 512
#define KBLK 4096                  // 64x64 blocks per image
#define TOTAL_BLK (IMG_N * KBLK)   // 262144
#define WG 256
#define NWG (TOTAL_BLK / WG)       // 1024
#define CHUNKS 16                  // workgroups per image in kC

__device__ __forceinline__ float wave_red(float v) {
#pragma unroll
    for (int o = 32; o > 0; o >>= 1) v += __shfl_down(v, o, 64);
    return v;
}

// ---------------- kernel A: per-block DC amplitude of target, partial sums ----
__global__ __launch_bounds__(WG) void kA(const float* __restrict__ tgt,
                                         float* __restrict__ partA) {
    int gid = blockIdx.x * WG + threadIdx.x;
    int n = gid >> 12;
    int k = gid & 4095;
    int bi = k >> 6, bj = k & 63;
    const float* p = tgt + (size_t)n * (IMG_H * IMG_W) + (size_t)(bi * 8) * IMG_W + bj * 8;
    float s = 0.f;
#pragma unroll
    for (int r = 0; r < 8; r++) {
        float4 a = *(const float4*)(p + (size_t)r * IMG_W);
        float4 b = *(const float4*)(p + (size_t)r * IMG_W + 4);
        s += ((a.x + a.y) + (a.z + a.w)) + ((b.x + b.y) + (b.z + b.w));
    }
    float dc = s * (1.0f / 64.0f);                 // rfft2 DC / b^2
    float amp = sqrtf((dc + EPSf) * (dc + EPSf) + EPSf * EPSf);
    float wv = wave_red(amp);
    __shared__ float red[4];
    if ((threadIdx.x & 63) == 0) red[threadIdx.x >> 6] = wv;
    __syncthreads();
    if (threadIdx.x == 0) partA[blockIdx.x] = (red[0] + red[1]) + (red[2] + red[3]);
}

// ---------------- kernel B: reduce 1024 partials -> avg_lum -------------------
__global__ __launch_bounds__(1024) void kB(const float* __restrict__ partA,
                                           float* __restrict__ avgOut) {
    float v = partA[threadIdx.x];
    float wv = wave_red(v);
    __shared__ float red[16];
    if ((threadIdx.x & 63) == 0) red[threadIdx.x >> 6] = wv;
    __syncthreads();
    if (threadIdx.x == 0) {
        float s = 0.f;
#pragma unroll
        for (int i = 0; i < 16; i++) s += red[i];
        avgOut[0] = s * (1.0f / (float)TOTAL_BLK);
    }
}

// ---------------- in-register 8x8 rFFT2 (scaled by 1/64) ---------------------
__device__ __forceinline__ void block_rfft2(const float* __restrict__ p,
                                            float cr[8][5], float ci[8][5]) {
    const float C = 0.70710678118654752440f;
    // row real FFT-8 -> 5 complex per row
#pragma unroll
    for (int r = 0; r < 8; r++) {
        float4 a = *(const float4*)(p + (size_t)r * IMG_W);      // x0..x3
        float4 b = *(const float4*)(p + (size_t)r * IMG_W + 4);  // x4..x7
        float s02 = a.x + b.x, d02 = a.x - b.x;   // x0 +- x4
        float s26 = a.z + b.z, d26 = a.z - b.z;   // x2 +- x6
        float s13 = a.y + b.y, d13 = a.y - b.y;   // x1 +- x5
        float s37 = a.w + b.w, d37 = a.w - b.w;   // x3 +- x7
        float e0 = s02 + s26, e2 = s02 - s26;
        float o0 = s13 + s37, o2 = s13 - s37;
        float cp = C * (d13 - d37), cm = C * (d13 + d37);
        cr[r][0] = e0 + o0;   ci[r][0] = 0.f;
        cr[r][1] = d02 + cp;  ci[r][1] = -d26 - cm;
        cr[r][2] = e2;        ci[r][2] = -o2;
        cr[r][3] = d02 - cp;  ci[r][3] = d26 - cm;
        cr[r][4] = e0 - o0;   ci[r][4] = 0.f;
    }
    // column complex FFT-8 per v, in place, scaled by 1/64
#pragma unroll
    for (int v = 0; v < 5; v++) {
        float t0r = cr[0][v] + cr[4][v], t0i = ci[0][v] + ci[4][v];
        float t1r = cr[0][v] - cr[4][v], t1i = ci[0][v] - ci[4][v];
        float t2r = cr[2][v] + cr[6][v], t2i = ci[2][v] + ci[6][v];
        float t3r = cr[2][v] - cr[6][v], t3i = ci[2][v] - ci[6][v];
        float E0r = t0r + t2r, E0i = t0i + t2i;
        float E2r = t0r - t2r, E2i = t0i - t2i;
        float E1r = t1r + t3i, E1i = t1i - t3r;   // t1 - i*t3
        float E3r = t1r - t3i, E3i = t1i + t3r;   // t1 + i*t3
        float u0r = cr[1][v] + cr[5][v], u0i = ci[1][v] + ci[5][v];
        float u1r = cr[1][v] - cr[5][v], u1i = ci[1][v] - ci[5][v];
        float u2r = cr[3][v] + cr[7][v], u2i = ci[3][v] + ci[7][v];
        float u3r = cr[3][v] - cr[7][v], u3i = ci[3][v] - ci[7][v];
        float O0r = u0r + u2r, O0i = u0i + u2i;
        float O2r = u0r - u2r, O2i = u0i - u2i;
        float O1r = u1r + u3i, O1i = u1i - u3r;
        float O3r = u1r - u3i, O3i = u1i + u3r;
        float W1r = C * (O1r + O1i), W1i = C * (O1i - O1r);  // W8^1 * O1
        float W2r = O2i,             W2i = -O2r;             // -i * O2
        float W3r = C * (O3i - O3r), W3i = -C * (O3r + O3i); // W8^3 * O3
        const float S = 1.0f / 64.0f;
        cr[0][v] = (E0r + O0r) * S; ci[0][v] = (E0i + O0i) * S;
        cr[1][v] = (E1r + W1r) * S; ci[1][v] = (E1i + W1i) * S;
        cr[2][v] = (E2r + W2r) * S; ci[2][v] = (E2i + W2i) * S;
        cr[3][v] = (E3r + W3r) * S; ci[3][v] = (E3i + W3i) * S;
        cr[4][v] = (E0r - O0r) * S; ci[4][v] = (E0i - O0i) * S;
        cr[5][v] = (E1r - W1r) * S; ci[5][v] = (E1i - W1i) * S;
        cr[6][v] = (E2r - W2r) * S; ci[6][v] = (E2i - W2i) * S;
        cr[7][v] = (E3r - W3r) * S; ci[7][v] = (E3i - W3i) * S;
    }
}

// ---------------- kernel C: main fused compute --------------------------------
__global__ __launch_bounds__(WG) void kC(const float* __restrict__ tgt,
                                         const float* __restrict__ inp,
                                         const float* __restrict__ t_tild,
                                         const float* __restrict__ alphaP,
                                         const float* __restrict__ wtP,
                                         const float* __restrict__ betaP,
                                         const float* __restrict__ wptP,
                                         const float* __restrict__ avgP,
                                         float* __restrict__ partW,
                                         float* __restrict__ partP) {
    __shared__ float t_tab[40], wp_tab[40];
    if (threadIdx.x < 40) {
        t_tab[threadIdx.x] = __expf(t_tild[threadIdx.x]);
        wp_tab[threadIdx.x] = __expf(wptP[threadIdx.x]);
    }
    __syncthreads();
    float alpha = alphaP[0];
    float w = 1.f / (1.f + __expf(-wtP[0]));
    float beta = betaP[0];
    float avg = avgP[0];
    bool b1 = (beta == 1.0f);

    int gid = blockIdx.x * WG + threadIdx.x;
    int n = gid >> 12, k = gid & 4095;
    int bi = k >> 6, bj = k & 63;
    size_t off = (size_t)n * (IMG_H * IMG_W) + (size_t)(bi * 8) * IMG_W + bj * 8;

    float c0r[8][5], c0i[8][5], c1r[8][5], c1i[8][5];
    block_rfft2(tgt + off, c0r, c0i);
    block_rfft2(inp + off, c1r, c1i);

    float amp00 = sqrtf((c0r[0][0] + EPSf) * (c0r[0][0] + EPSf) +
                        (c0i[0][0] + EPSf) * (c0i[0][0] + EPSf));
    float lum = __powf((amp00 + EPSf) / (avg + EPSf), alpha);

    float sumW = 0.f, sumP = 0.f;
#pragma unroll
    for (int u = 0; u < 8; u++) {
#pragma unroll
        for (int v = 0; v < 5; v++) {
            float r0 = c0r[u][v] + EPSf, i0e = c0i[u][v] + EPSf;
            float r1 = c1r[u][v] + EPSf, i1e = c1i[u][v] + EPSf;
            float a0 = sqrtf(r0 * r0 + i0e * i0e);
            float a1 = sqrtf(r1 * r1 + i1e * i1e);
            float t_l = t_tab[u * 5 + v] * lum;
            float bb = __powf(a0 + EPSf, w) * __powf(t_l, 1.f - w);
            float f0 = 1.f / (1.f + __expf(bb - t_l));   // softmax weight of t_l
            float s = t_l * f0 + bb * (1.f - f0);
            float term = fabsf((a0 - a1) / s) + EPSf;
            if (!b1) term = __powf(term, beta);
            sumW += term + EPSf;
            // phase: cos(p0 - p1) via dot/norms (i without EPS, r with EPS)
            float i0 = c0i[u][v], i1 = c1i[u][v];
            float dot = r0 * r1 + i0 * i1;
            float nn = fmaxf((r0 * r0 + i0 * i0) * (r1 * r1 + i1 * i1), 1e-36f);
            float cosd = dot * rsqrtf(nn);
            cosd = fminf(fmaxf(cosd * (1.f - 1e-7f), -1.f), 1.f);
            sumP += acosf(cosd) * wp_tab[u * 5 + v];
        }
    }
    float wW = wave_red(sumW);
    float wP = wave_red(sumP);
    __shared__ float redW[4], redP[4];
    if ((threadIdx.x & 63) == 0) { redW[threadIdx.x >> 6] = wW; redP[threadIdx.x >> 6] = wP; }
    __syncthreads();
    if (threadIdx.x == 0) {
        partW[blockIdx.x] = (redW[0] + redW[1]) + (redW[2] + redW[3]);
        partP[blockIdx.x] = (redP[0] + redP[1]) + (redP[2] + redP[3]);
    }
}

// ---------------- kernel D: per-image final ----------------------------------
__global__ __launch_bounds__(64) void kD(const float* __restrict__ partW,
                                         const float* __restrict__ partP,
                                         const float* __restrict__ betaP,
                                         float* __restrict__ out) {
    int n = threadIdx.x;
    float sW = 0.f, sP = 0.f;
#pragma unroll
    for (int c = 0; c < CHUNKS; c++) {
        sW += partW[n * CHUNKS + c];
        sP += partP[n * CHUNKS + c];
    }
    float beta = betaP[0];
    float wat = (beta == 1.0f) ? sW : __powf(sW, 1.0f / beta);
    out[n] = wat + sP;
}

extern "C" void kernel_launch(void* const* d_in, const int* in_sizes, int n_in,
                              void* d_out, int out_size, void* d_ws, size_t ws_size,
                              hipStream_t stream) {
    const float* inp    = (const float*)d_in[0];
    const float* tgt    = (const float*)d_in[1];
    const float* t_tild = (const float*)d_in[2];
    const float* alphaP = (const float*)d_in[3];
    const float* wtP    = (const float*)d_in[4];
    const float* betaP  = (const float*)d_in[5];
    const float* wptP   = (const float*)d_in[6];
    float* out = (float*)d_out;
    float* ws = (float*)d_ws;
    float* partA = ws;           // [1024]
    float* avgV  = ws + 1024;    // [1]
    float* partW = ws + 1056;    // [1024]
    float* partP = ws + 2080;    // [1024]

    hipLaunchKernelGGL(kA, dim3(NWG), dim3(WG), 0, stream, tgt, partA);
    hipLaunchKernelGGL(kB, dim3(1), dim3(1024), 0, stream, partA, avgV);
    hipLaunchKernelGGL(kC, dim3(NWG), dim3(WG), 0, stream, tgt, inp, t_tild,
                       alphaP, wtP, betaP, wptP, avgV, partW, partP);
    hipLaunchKernelGGL(kD, dim3(1), dim3(64), 0, stream, partW, partP, betaP, out);
}

// Round 2
// 185.918 us; speedup vs baseline: 1.5082x; 1.5082x over previous
//
#include <hip/hip_runtime.h>
#include <math.h>

#define EPSf 1e-10f
#define IMG_N 64
#define IMG_H 512
#define IMG_W 512
#define KBLK 4096                  // 64x64 blocks per image
#define TOTAL_BLK (IMG_N * KBLK)   // 262144
#define WG 256
#define NWG (TOTAL_BLK / WG)       // 1024
#define CHUNKS 16                  // workgroups per image in kC

__device__ __forceinline__ float wave_red(float v) {
#pragma unroll
    for (int o = 32; o > 0; o >>= 1) v += __shfl_down(v, o, 64);
    return v;
}

// ---------------- kernel A: per-block DC amplitude of target, partial sums ----
__global__ __launch_bounds__(WG) void kA(const float* __restrict__ tgt,
                                         float* __restrict__ partA) {
    int gid = blockIdx.x * WG + threadIdx.x;
    int n = gid >> 12;
    int k = gid & 4095;
    int bi = k >> 6, bj = k & 63;
    const float* p = tgt + (size_t)n * (IMG_H * IMG_W) + (size_t)(bi * 8) * IMG_W + bj * 8;
    float s = 0.f;
#pragma unroll
    for (int r = 0; r < 8; r++) {
        float4 a = *(const float4*)(p + (size_t)r * IMG_W);
        float4 b = *(const float4*)(p + (size_t)r * IMG_W + 4);
        s += ((a.x + a.y) + (a.z + a.w)) + ((b.x + b.y) + (b.z + b.w));
    }
    float dc = s * (1.0f / 64.0f);                 // rfft2 DC / b^2
    float amp = sqrtf((dc + EPSf) * (dc + EPSf) + EPSf * EPSf);
    float wv = wave_red(amp);
    __shared__ float red[4];
    if ((threadIdx.x & 63) == 0) red[threadIdx.x >> 6] = wv;
    __syncthreads();
    if (threadIdx.x == 0) partA[blockIdx.x] = (red[0] + red[1]) + (red[2] + red[3]);
}

// ---------------- kernel B: reduce 1024 partials -> avg_lum -------------------
__global__ __launch_bounds__(1024) void kB(const float* __restrict__ partA,
                                           float* __restrict__ avgOut) {
    float v = partA[threadIdx.x];
    float wv = wave_red(v);
    __shared__ float red[16];
    if ((threadIdx.x & 63) == 0) red[threadIdx.x >> 6] = wv;
    __syncthreads();
    if (threadIdx.x == 0) {
        float s = 0.f;
#pragma unroll
        for (int i = 0; i < 16; i++) s += red[i];
        avgOut[0] = s * (1.0f / (float)TOTAL_BLK);
    }
}

// row real FFT-8, compact 8-float output, scaled by 1/64
// y = [c0, c1r, c1i, c2r, c2i, c3r, c3i, c4]
__device__ __forceinline__ void rowfft8(float4 a, float4 b, float y[8]) {
    const float C = 0.70710678118654752440f;
    const float S = 1.0f / 64.0f;
    float s02 = a.x + b.x, d02 = a.x - b.x;
    float s26 = a.z + b.z, d26 = a.z - b.z;
    float s13 = a.y + b.y, d13 = a.y - b.y;
    float s37 = a.w + b.w, d37 = a.w - b.w;
    float e0 = s02 + s26, e2 = s02 - s26;
    float o0 = s13 + s37, o2 = s13 - s37;
    float cp = C * (d13 - d37), cm = C * (d13 + d37);
    y[0] = S * (e0 + o0);
    y[1] = S * (d02 + cp);
    y[2] = S * (-d26 - cm);
    y[3] = S * e2;
    y[4] = S * (-o2);
    y[5] = S * (d02 - cp);
    y[6] = S * (d26 - cm);
    y[7] = S * (e0 - o0);
}

// complex FFT-8 (unscaled)
__device__ __forceinline__ void cfft8(const float xr[8], const float xi[8],
                                      float Xr[8], float Xi[8]) {
    const float C = 0.70710678118654752440f;
    float t0r = xr[0] + xr[4], t0i = xi[0] + xi[4];
    float t1r = xr[0] - xr[4], t1i = xi[0] - xi[4];
    float t2r = xr[2] + xr[6], t2i = xi[2] + xi[6];
    float t3r = xr[2] - xr[6], t3i = xi[2] - xi[6];
    float E0r = t0r + t2r, E0i = t0i + t2i;
    float E2r = t0r - t2r, E2i = t0i - t2i;
    float E1r = t1r + t3i, E1i = t1i - t3r;   // t1 - i*t3
    float E3r = t1r - t3i, E3i = t1i + t3r;   // t1 + i*t3
    float u0r = xr[1] + xr[5], u0i = xi[1] + xi[5];
    float u1r = xr[1] - xr[5], u1i = xi[1] - xi[5];
    float u2r = xr[3] + xr[7], u2i = xi[3] + xi[7];
    float u3r = xr[3] - xr[7], u3i = xi[3] - xi[7];
    float O0r = u0r + u2r, O0i = u0i + u2i;
    float O2r = u0r - u2r, O2i = u0i - u2i;
    float O1r = u1r + u3i, O1i = u1i - u3r;
    float O3r = u1r - u3i, O3i = u1i + u3r;
    float W1r = C * (O1r + O1i), W1i = C * (O1i - O1r);  // W8^1 * O1
    float W2r = O2i,             W2i = -O2r;             // -i * O2
    float W3r = C * (O3i - O3r), W3i = -C * (O3r + O3i); // W8^3 * O3
    Xr[0] = E0r + O0r; Xi[0] = E0i + O0i;
    Xr[1] = E1r + W1r; Xi[1] = E1i + W1i;
    Xr[2] = E2r + W2r; Xi[2] = E2i + W2i;
    Xr[3] = E3r + W3r; Xi[3] = E3i + W3i;
    Xr[4] = E0r - O0r; Xi[4] = E0i - O0i;
    Xr[5] = E1r - W1r; Xi[5] = E1i - W1i;
    Xr[6] = E2r - W2r; Xi[6] = E2i - W2i;
    Xr[7] = E3r - W3r; Xi[7] = E3i - W3i;
}

// ---------------- kernel C: main fused compute --------------------------------
__global__ __launch_bounds__(WG, 2) void kC(const float* __restrict__ tgt,
                                            const float* __restrict__ inp,
                                            const float* __restrict__ t_tild,
                                            const float* __restrict__ alphaP,
                                            const float* __restrict__ wtP,
                                            const float* __restrict__ betaP,
                                            const float* __restrict__ wptP,
                                            const float* __restrict__ avgP,
                                            float* __restrict__ partW,
                                            float* __restrict__ partP) {
    __shared__ float t_tab[40], wp_tab[40];
    if (threadIdx.x < 40) {
        t_tab[threadIdx.x] = __expf(t_tild[threadIdx.x]);
        wp_tab[threadIdx.x] = __expf(wptP[threadIdx.x]);
    }
    __syncthreads();
    float alpha = alphaP[0];
    float w = 1.f / (1.f + __expf(-wtP[0]));
    float beta = betaP[0];
    float avg = avgP[0];
    bool b1 = (beta == 1.0f);

    int gid = blockIdx.x * WG + threadIdx.x;
    int n = gid >> 12, k = gid & 4095;
    int bi = k >> 6, bj = k & 63;
    size_t off = (size_t)n * (IMG_H * IMG_W) + (size_t)(bi * 8) * IMG_W + bj * 8;

    // row FFTs, compact state: 64 floats per image
    float y0[8][8], y1[8][8];
    const float* p0 = tgt + off;
    const float* p1 = inp + off;
#pragma unroll
    for (int r = 0; r < 8; r++) {
        float4 a = *(const float4*)(p0 + (size_t)r * IMG_W);
        float4 b = *(const float4*)(p0 + (size_t)r * IMG_W + 4);
        rowfft8(a, b, y0[r]);
    }
#pragma unroll
    for (int r = 0; r < 8; r++) {
        float4 a = *(const float4*)(p1 + (size_t)r * IMG_W);
        float4 b = *(const float4*)(p1 + (size_t)r * IMG_W + 4);
        rowfft8(a, b, y1[r]);
    }

    float sumW = 0.f, sumP = 0.f;
    float lum = 0.f;
#pragma unroll
    for (int v = 0; v < 5; v++) {
        // gather column v (component pair); v=0 -> comp 0 (real), v=4 -> comp 7 (real)
        float x0r[8], x0i[8], x1r[8], x1i[8];
#pragma unroll
        for (int r = 0; r < 8; r++) {
            if (v == 0)      { x0r[r] = y0[r][0]; x0i[r] = 0.f;
                               x1r[r] = y1[r][0]; x1i[r] = 0.f; }
            else if (v == 4) { x0r[r] = y0[r][7]; x0i[r] = 0.f;
                               x1r[r] = y1[r][7]; x1i[r] = 0.f; }
            else             { x0r[r] = y0[r][2 * v - 1]; x0i[r] = y0[r][2 * v];
                               x1r[r] = y1[r][2 * v - 1]; x1i[r] = y1[r][2 * v]; }
        }
        float X0r[8], X0i[8], X1r[8], X1i[8];
        cfft8(x0r, x0i, X0r, X0i);
        cfft8(x1r, x1i, X1r, X1i);

        if (v == 0) {
            // c0 amp at (u=0,v=0); X0i[0] == 0 structurally
            float rr = X0r[0] + EPSf, ii = X0i[0] + EPSf;
            float amp00 = sqrtf(rr * rr + ii * ii);
            lum = __powf((amp00 + EPSf) / (avg + EPSf), alpha);
        }

#pragma unroll
        for (int u = 0; u < 8; u++) {
            float r0 = X0r[u] + EPSf, i0e = X0i[u] + EPSf;
            float r1 = X1r[u] + EPSf, i1e = X1i[u] + EPSf;
            float a0 = sqrtf(r0 * r0 + i0e * i0e);
            float a1 = sqrtf(r1 * r1 + i1e * i1e);
            float t_l = t_tab[u * 5 + v] * lum;
            float bb = __powf(a0 + EPSf, w) * __powf(t_l, 1.f - w);
            float f0 = 1.f / (1.f + __expf(bb - t_l));   // softmax weight of t_l
            float s = t_l * f0 + bb * (1.f - f0);
            float term = fabsf((a0 - a1) / s) + EPSf;
            if (!b1) term = __powf(term, beta);
            sumW += term + EPSf;
            // phase: cos(p0 - p1) via dot/norms (imag WITHOUT eps, real WITH eps)
            float i0 = X0i[u], i1 = X1i[u];
            float dot = r0 * r1 + i0 * i1;
            float nn = fmaxf((r0 * r0 + i0 * i0) * (r1 * r1 + i1 * i1), 1e-36f);
            float cosd = dot * rsqrtf(nn);
            cosd = fminf(fmaxf(cosd * (1.f - 1e-7f), -1.f), 1.f);
            sumP += acosf(cosd) * wp_tab[u * 5 + v];
        }
    }

    float wW = wave_red(sumW);
    float wP = wave_red(sumP);
    __shared__ float redW[4], redP[4];
    if ((threadIdx.x & 63) == 0) { redW[threadIdx.x >> 6] = wW; redP[threadIdx.x >> 6] = wP; }
    __syncthreads();
    if (threadIdx.x == 0) {
        partW[blockIdx.x] = (redW[0] + redW[1]) + (redW[2] + redW[3]);
        partP[blockIdx.x] = (redP[0] + redP[1]) + (redP[2] + redP[3]);
    }
}

// ---------------- kernel D: per-image final ----------------------------------
__global__ __launch_bounds__(64) void kD(const float* __restrict__ partW,
                                         const float* __restrict__ partP,
                                         const float* __restrict__ betaP,
                                         float* __restrict__ out) {
    int n = threadIdx.x;
    float sW = 0.f, sP = 0.f;
#pragma unroll
    for (int c = 0; c < CHUNKS; c++) {
        sW += partW[n * CHUNKS + c];
        sP += partP[n * CHUNKS + c];
    }
    float beta = betaP[0];
    float wat = (beta == 1.0f) ? sW : __powf(sW, 1.0f / beta);
    out[n] = wat + sP;
}

extern "C" void kernel_launch(void* const* d_in, const int* in_sizes, int n_in,
                              void* d_out, int out_size, void* d_ws, size_t ws_size,
                              hipStream_t stream) {
    const float* inp    = (const float*)d_in[0];
    const float* tgt    = (const float*)d_in[1];
    const float* t_tild = (const float*)d_in[2];
    const float* alphaP = (const float*)d_in[3];
    const float* wtP    = (const float*)d_in[4];
    const float* betaP  = (const float*)d_in[5];
    const float* wptP   = (const float*)d_in[6];
    float* out = (float*)d_out;
    float* ws = (float*)d_ws;
    float* partA = ws;           // [1024]
    float* avgV  = ws + 1024;    // [1]
    float* partW = ws + 1056;    // [1024]
    float* partP = ws + 2080;    // [1024]

    hipLaunchKernelGGL(kA, dim3(NWG), dim3(WG), 0, stream, tgt, partA);
    hipLaunchKernelGGL(kB, dim3(1), dim3(1024), 0, stream, partA, avgV);
    hipLaunchKernelGGL(kC, dim3(NWG), dim3(WG), 0, stream, tgt, inp, t_tild,
                       alphaP, wtP, betaP, wptP, avgV, partW, partP);
    hipLaunchKernelGGL(kD, dim3(1), dim3(64), 0, stream, partW, partP, betaP, out);
}